// Round 5
// baseline (430.399 us; speedup 1.0000x reference)
//
#include <hip/hip_runtime.h>
#include <stdint.h>

#define DN 128
#define CAPN 64          // padded slots per node (deg ~Poisson(16), max ~50 at n=100K)

__host__ __device__ static inline int divup(int a, int b){ return (a+b-1)/b; }

typedef __attribute__((ext_vector_type(8))) short bf16x8;
typedef __attribute__((ext_vector_type(4))) float floatx4;

__device__ __forceinline__ unsigned short f2bf(float f){
  unsigned int x = __float_as_uint(f);
  unsigned int r = x + 0x7fffu + ((x >> 16) & 1u);   // RNE
  return (unsigned short)(r >> 16);
}
__device__ __forceinline__ unsigned int pack2(unsigned short a, unsigned short b){
  return (unsigned int)a | ((unsigned int)b << 16);
}

// ---------------- fp32 -> bf16 conversion (x + 4 weight mats) + cnt zeroing ----------------

__global__ __launch_bounds__(256)
void convert_all(const float* __restrict__ x,
                 const float* __restrict__ w0, const float* __restrict__ w1,
                 const float* __restrict__ w2, const float* __restrict__ w3,
                 unsigned short* __restrict__ xb, unsigned short* __restrict__ Wb,
                 int* __restrict__ cnt, int n, int count8){
  int i = blockIdx.x*256 + threadIdx.x;
  if (i < n) cnt[i] = 0;                        // zero per-node cursors for scatter
  const float* sp; unsigned short* dp; int off;
  if (i < count8){ sp = x; dp = xb; off = i; }
  else {
    int tid = i - count8;                       // 0..8191 -> weight mats
    if (tid >= 8192) return;
    int mat = tid >> 11; off = tid & 2047;
    sp = (mat==0)?w0:(mat==1)?w1:(mat==2)?w2:w3;
    dp = Wb + (size_t)mat*16384;
  }
  const float4* s = (const float4*)sp + (size_t)off*2;
  float4 a = s[0], b = s[1];
  uint4 o;
  o.x = pack2(f2bf(a.x), f2bf(a.y));
  o.y = pack2(f2bf(a.z), f2bf(a.w));
  o.z = pack2(f2bf(b.x), f2bf(b.y));
  o.w = pack2(f2bf(b.z), f2bf(b.w));
  ((uint4*)dp)[off] = o;
}

// ---------------- single-pass per-node scatter (padded slots, node-sorted by construction) --
// pos = atomicAdd(cnt[d]) reserves the final slot directly: no histogram, no scan, no
// bucket sort pass. Cursor array is 400 KB (L2-hot), ~16 hits/counter -> low contention.
__global__ __launch_bounds__(256)
void scatter_node(const int* __restrict__ src, const int* __restrict__ dst,
                  int* __restrict__ cnt, int* __restrict__ slots, int E){
  int i = blockIdx.x*256 + threadIdx.x;
  int n4 = E >> 2;
  if (i < n4){
    int4 d4 = ((const int4*)dst)[i];
    int4 s4 = ((const int4*)src)[i];
    int dd[4] = {d4.x, d4.y, d4.z, d4.w};
    int ss[4] = {s4.x, s4.y, s4.z, s4.w};
    #pragma unroll
    for (int j=0;j<4;j++){
      int pos = atomicAdd(&cnt[dd[j]], 1);
      if (pos < CAPN)                            // 12-sigma guard; cannot trigger
        slots[(size_t)dd[j]*CAPN + pos] = ss[j];
    }
  }
  // tail E%4 (E=1.6M is divisible by 4; kept for generality)
  int e = (n4<<2) + i;
  if (i < (E & 3)){
    int d = dst[e];
    int pos = atomicAdd(&cnt[d], 1);
    if (pos < CAPN) slots[(size_t)d*CAPN + pos] = src[e];
  }
}

// ---------------- mean aggregation (padded per-node slots, 16-lane groups) ----------------
// 16 lanes per node; lane l holds cols [8l,8l+8) as one 16B chunk. Inner gather loop
// identical to the proven r0 kernel; index source is now slots[g*64..] via int4 loads.
__global__ __launch_bounds__(256)
void aggregate_csr(const unsigned short* __restrict__ xb, const int* __restrict__ cnt,
                   const int* __restrict__ slots, unsigned short* __restrict__ aggb, int n){
  int g = (blockIdx.x*256 + threadIdx.x) >> 4;
  int l = threadIdx.x & 15;
  if (g >= n) return;
  int deg = min(cnt[g], CAPN);
  const int* sl = slots + (size_t)g*CAPN;
  float acc[8] = {0,0,0,0,0,0,0,0};
  #define ACCUM(u) { unsigned int w;                                   \
      w=(u).x; acc[0]+=__uint_as_float(w<<16); acc[1]+=__uint_as_float(w&0xffff0000u); \
      w=(u).y; acc[2]+=__uint_as_float(w<<16); acc[3]+=__uint_as_float(w&0xffff0000u); \
      w=(u).z; acc[4]+=__uint_as_float(w<<16); acc[5]+=__uint_as_float(w&0xffff0000u); \
      w=(u).w; acc[6]+=__uint_as_float(w<<16); acc[7]+=__uint_as_float(w&0xffff0000u); }
  int p = 0;
  for (; p+4 <= deg; p += 4){
    int4 si = *(const int4*)(sl + p);            // 16B-aligned (g*256B base)
    uint4 u0 = ((const uint4*)(xb + (size_t)si.x*DN))[l];
    uint4 u1 = ((const uint4*)(xb + (size_t)si.y*DN))[l];
    uint4 u2 = ((const uint4*)(xb + (size_t)si.z*DN))[l];
    uint4 u3 = ((const uint4*)(xb + (size_t)si.w*DN))[l];
    ACCUM(u0) ACCUM(u1) ACCUM(u2) ACCUM(u3)
  }
  for (; p < deg; ++p){
    int s0 = sl[p];
    uint4 u0 = ((const uint4*)(xb + (size_t)s0*DN))[l];
    ACCUM(u0)
  }
  #undef ACCUM
  float inv = 1.f / fmaxf((float)deg, 1.f);
  uint4 o;
  o.x = pack2(f2bf(acc[0]*inv), f2bf(acc[1]*inv));
  o.y = pack2(f2bf(acc[2]*inv), f2bf(acc[3]*inv));
  o.z = pack2(f2bf(acc[4]*inv), f2bf(acc[5]*inv));
  o.w = pack2(f2bf(acc[6]*inv), f2bf(acc[7]*inv));
  ((uint4*)(aggb + (size_t)g*DN))[l] = o;
}

// ---------------- dual-GEMM via bf16 MFMA, LDS-coalesced epilogue ----------------
// Epilogue change: stage the 16x128 output tile in LDS, then emit contiguous 16B
// dwordx4 stores (was: 12.8M scattered 2B stores per layer).
template<bool RELU, bool OUT_BF16>
__global__ __launch_bounds__(256)
void gemm_mfma(const unsigned short* __restrict__ A1, const unsigned short* __restrict__ W1b,
               const unsigned short* __restrict__ A2, const unsigned short* __restrict__ W2b,
               const float* __restrict__ bias, void* __restrict__ out,
               int rt_total, int rt_per_block)
{
  __shared__ unsigned char obuf[8192];           // 16x128 tile: bf16=4KB, fp32=8KB
  int t = threadIdx.x;
  int wave = t >> 6;
  int lane = t & 63;
  int m = lane & 15, quad = lane >> 4;

  bf16x8 Bf[2][2][4];   // persistent B fragments: [ct2][mat][kc]
  {
    const unsigned short* Ws[2] = {W1b, W2b};
    #pragma unroll
    for (int c2=0;c2<2;c2++){
      int col = wave*32 + c2*16 + m;
      #pragma unroll
      for (int mat=0;mat<2;mat++){
        const unsigned short* wrow = Ws[mat] + (size_t)col*DN + quad*8;
        #pragma unroll
        for (int kc=0;kc<4;kc++)
          Bf[c2][mat][kc] = *(const bf16x8*)(wrow + kc*32);
      }
    }
  }
  float bv0 = bias[wave*32 + m];
  float bv1 = bias[wave*32 + 16 + m];

  int rt_begin = blockIdx.x * rt_per_block;
  int rt_end = rt_begin + rt_per_block; if (rt_end > rt_total) rt_end = rt_total;

  for (int rt = rt_begin; rt < rt_end; ++rt){
    const unsigned short* a1p = A1 + ((size_t)(rt*16 + m))*DN + quad*8;
    const unsigned short* a2p = A2 + ((size_t)(rt*16 + m))*DN + quad*8;
    bf16x8 Af[2][4];
    #pragma unroll
    for (int kc=0;kc<4;kc++){
      Af[0][kc] = *(const bf16x8*)(a1p + kc*32);
      Af[1][kc] = *(const bf16x8*)(a2p + kc*32);
    }
    __syncthreads();   // drains loads; all waves past load phase before stores
    floatx4 acc0 = {0.f,0.f,0.f,0.f}, acc1 = {0.f,0.f,0.f,0.f};
    #pragma unroll
    for (int mat=0; mat<2; mat++)
      #pragma unroll
      for (int kc=0; kc<4; kc++){
        acc0 = __builtin_amdgcn_mfma_f32_16x16x32_bf16(Af[mat][kc], Bf[0][mat][kc], acc0, 0,0,0);
        acc1 = __builtin_amdgcn_mfma_f32_16x16x32_bf16(Af[mat][kc], Bf[1][mat][kc], acc1, 0,0,0);
      }
    if (OUT_BF16){
      unsigned short (*ob)[128] = (unsigned short (*)[128])obuf;
      #pragma unroll
      for (int r=0;r<4;r++){
        float v0 = acc0[r] + bv0;
        float v1 = acc1[r] + bv1;
        if (RELU){ v0 = fmaxf(v0, 0.f); v1 = fmaxf(v1, 0.f); }
        ob[quad*4+r][wave*32 + m]      = f2bf(v0);
        ob[quad*4+r][wave*32 + 16 + m] = f2bf(v1);
      }
      __syncthreads();
      // 16 rows x 128 cols bf16 = 4KB contiguous at row rt*16
      ((uint4*)((unsigned short*)out + (size_t)rt*16*DN))[t & 255] = ((const uint4*)obuf)[t & 255];
      __syncthreads();   // WAR: obuf reused next tile
    } else {
      float (*of)[128] = (float (*)[128])obuf;
      #pragma unroll
      for (int r=0;r<4;r++){
        float v0 = acc0[r] + bv0;
        float v1 = acc1[r] + bv1;
        if (RELU){ v0 = fmaxf(v0, 0.f); v1 = fmaxf(v1, 0.f); }
        of[quad*4+r][wave*32 + m]      = v0;
        of[quad*4+r][wave*32 + 16 + m] = v1;
      }
      __syncthreads();
      uint4* og = (uint4*)((float*)out + (size_t)rt*16*DN);   // 8KB contiguous
      og[t]       = ((const uint4*)obuf)[t];
      og[t + 256] = ((const uint4*)obuf)[t + 256];
      __syncthreads();
    }
  }
}

// ---------------- launch ----------------

extern "C" void kernel_launch(void* const* d_in, const int* in_sizes, int n_in,
                              void* d_out, int out_size, void* d_ws, size_t ws_size,
                              hipStream_t stream) {
  const float* x   = (const float*)d_in[0];
  const int*   ei  = (const int*)d_in[1];
  const float* Wl1 = (const float*)d_in[2];
  const float* bl1 = (const float*)d_in[3];
  const float* Wr1 = (const float*)d_in[4];
  const float* Wl2 = (const float*)d_in[5];
  const float* bl2 = (const float*)d_in[6];
  const float* Wr2 = (const float*)d_in[7];

  const int n = in_sizes[0] / DN;     // 100000
  const int E = in_sizes[1] / 2;      // 1600000
  const int* src = ei;
  const int* dst = ei + E;

  // workspace: cnt | slots(per-node padded) | Wb | xb | aggb [| hb]
  char* ws = (char*)d_ws;
  char* ws_end = ws + ws_size;
  int* cnt = (int*)ws;  ws += (size_t)n*4;
  ws = (char*)(((uintptr_t)ws + 255) & ~(uintptr_t)255);
  int* slots = (int*)ws; ws += (size_t)n*CAPN*4;               // 25.6 MB
  ws = (char*)(((uintptr_t)ws + 255) & ~(uintptr_t)255);
  unsigned short* Wb   = (unsigned short*)ws; ws += 4*16384*2;
  unsigned short* xb   = (unsigned short*)ws; ws += (size_t)n*DN*2;
  unsigned short* aggb = (unsigned short*)ws; ws += (size_t)n*DN*2;
  unsigned short* hb = xb;   // in-place fallback (never taken at current ws_size)
  if (ws + (size_t)n*DN*2 <= ws_end) { hb = (unsigned short*)ws; ws += (size_t)n*DN*2; }

  unsigned short* Wl1b = Wb;
  unsigned short* Wr1b = Wb + 16384;
  unsigned short* Wl2b = Wb + 2*16384;
  unsigned short* Wr2b = Wb + 3*16384;

  const int count8 = n*DN/8;
  convert_all<<<divup(count8 + 8192, 256),256,0,stream>>>(x, Wl1, Wr1, Wl2, Wr2, xb, Wb, cnt, n, count8);
  scatter_node<<<divup(E/4, 256),256,0,stream>>>(src, dst, cnt, slots, E);

  const int rt_total = n / 16;                  // 6250
  const int rt_per_block = 5;
  const int gblocks = divup(rt_total, rt_per_block);
  const int agrid = divup(n*16, 256);           // 6250

  // layer 1: h = relu(agg@Wl1^T + x@Wr1^T + b1), bf16 out
  aggregate_csr<<<agrid,256,0,stream>>>(xb, cnt, slots, aggb, n);
  gemm_mfma<true, true ><<<gblocks,256,0,stream>>>(aggb, Wl1b, xb, Wr1b, bl1, hb, rt_total, rt_per_block);
  // layer 2: out = agg@Wl2^T + h@Wr2^T + b2, fp32 out
  aggregate_csr<<<agrid,256,0,stream>>>(hb, cnt, slots, aggb, n);
  gemm_mfma<false,false><<<gblocks,256,0,stream>>>(aggb, Wl2b, hb, Wr2b, bl2, d_out, rt_total, rt_per_block);
}

// Round 6
// 359.828 us; speedup vs baseline: 1.1961x; 1.1961x over previous
//
#include <hip/hip_runtime.h>
#include <stdint.h>

#define DN 128
#define NBITS 6          // 64 nodes per bucket
#define BNODES 64
#define HBMAX 2048       // LDS array bound for bucket counters (nbuck <= 1563)
#define CAP 1536         // padded bucket capacity (bucket load ~Poisson(1024), max ~1150)
#define NSL 256          // edge slices for scatter

__host__ __device__ static inline int divup(int a, int b){ return (a+b-1)/b; }

typedef __attribute__((ext_vector_type(8))) short bf16x8;
typedef __attribute__((ext_vector_type(4))) float floatx4;

__device__ __forceinline__ unsigned short f2bf(float f){
  unsigned int x = __float_as_uint(f);
  unsigned int r = x + 0x7fffu + ((x >> 16) & 1u);   // RNE
  return (unsigned short)(r >> 16);
}
__device__ __forceinline__ unsigned int pack2(unsigned short a, unsigned short b){
  return (unsigned int)a | ((unsigned int)b << 16);
}

// ---------------- fp32 -> bf16 conversion (x + 4 weight mats) + gcur zeroing ----------------

__global__ __launch_bounds__(256)
void convert_all(const float* __restrict__ x,
                 const float* __restrict__ w0, const float* __restrict__ w1,
                 const float* __restrict__ w2, const float* __restrict__ w3,
                 unsigned short* __restrict__ xb, unsigned short* __restrict__ Wb,
                 int* __restrict__ gcur, int nbuck, int count8){
  int i = blockIdx.x*256 + threadIdx.x;
  if (i < nbuck) gcur[i] = 0;                   // zero bucket cursors for scatter
  const float* sp; unsigned short* dp; int off;
  if (i < count8){ sp = x; dp = xb; off = i; }
  else {
    int tid = i - count8;                       // 0..8191 -> weight mats
    if (tid >= 8192) return;
    int mat = tid >> 11; off = tid & 2047;
    sp = (mat==0)?w0:(mat==1)?w1:(mat==2)?w2:w3;
    dp = Wb + (size_t)mat*16384;
  }
  const float4* s = (const float4*)sp + (size_t)off*2;
  float4 a = s[0], b = s[1];
  uint4 o;
  o.x = pack2(f2bf(a.x), f2bf(a.y));
  o.y = pack2(f2bf(a.z), f2bf(a.w));
  o.z = pack2(f2bf(b.x), f2bf(b.y));
  o.w = pack2(f2bf(b.z), f2bf(b.w));
  ((uint4*)dp)[off] = o;
}

// ---------------- single-kernel bucket scatter (padded buckets, atomic reservation) ----------
// NSL slice-blocks. Pass 1: LDS histogram of this slice. Reserve: one global atomicAdd
// per (slice,bucket) claims a contiguous range inside bucket b's fixed region [b*CAP,...).
// Pass 2: re-read slice (L2/L3-hot, edge list is 12.8 MB) and scatter via LDS cursors.
__global__ __launch_bounds__(256)
void scatter_atomic(const int* __restrict__ src, const int* __restrict__ dst,
                    int* __restrict__ gcur, unsigned int* __restrict__ packed,
                    int E, int nbuck){
  __shared__ int h[HBMAX];
  __shared__ int cur[HBMAX];
  int s = blockIdx.x, t = threadIdx.x;
  for (int i=t; i<nbuck; i+=256) h[i] = 0;
  __syncthreads();
  int n4 = E >> 2, per4 = divup(n4, NSL);
  int lo = s*per4, hi = min(lo+per4, n4);
  const int4* dst4 = (const int4*)dst;
  for (int i = lo + t; i < hi; i += 256){
    int4 d4 = dst4[i];
    atomicAdd(&h[d4.x >> NBITS], 1);
    atomicAdd(&h[d4.y >> NBITS], 1);
    atomicAdd(&h[d4.z >> NBITS], 1);
    atomicAdd(&h[d4.w >> NBITS], 1);
  }
  if (s == NSL-1){  // global tail E%4
    for (int e = (n4<<2) + t; e < E; e += 256)
      atomicAdd(&h[dst[e] >> NBITS], 1);
  }
  __syncthreads();
  for (int i=t; i<nbuck; i+=256){
    int c = h[i];
    int base = c ? atomicAdd(&gcur[i], c) : 0;
    cur[i] = i*CAP + base;
  }
  __syncthreads();
  const int4* src4 = (const int4*)src;
  for (int i = lo + t; i < hi; i += 256){
    int4 d4 = dst4[i];
    int4 s4 = src4[i];
    int dd[4] = {d4.x, d4.y, d4.z, d4.w};
    int ss[4] = {s4.x, s4.y, s4.z, s4.w};
    #pragma unroll
    for (int j=0;j<4;j++){
      int d = dd[j], b = d >> NBITS;
      int pos = atomicAdd(&cur[b], 1);
      if (pos < (b+1)*CAP)   // overflow guard (cannot trigger at 8-sigma margin)
        packed[pos] = (unsigned)ss[j] | ((unsigned)(d & (BNODES-1)) << 17);
    }
  }
  if (s == NSL-1){
    for (int e = (n4<<2) + t; e < E; e += 256){
      int d = dst[e], b = d >> NBITS;
      int pos = atomicAdd(&cur[b], 1);
      if (pos < (b+1)*CAP)
        packed[pos] = (unsigned)src[e] | ((unsigned)(d & (BNODES-1)) << 17);
    }
  }
}

// ---------------- per-bucket node sort, IN-PLACE -> csr (same buffer) + nodeOff2 ------------
// Block per bucket. Entries staged into <=6 regs/thread before any write (reads complete
// before first __syncthreads -> in-place rewrite is safe). Emits int2{beg,end} per node.
__global__ __launch_bounds__(256)
void node_sort(const int* __restrict__ gcur, unsigned int* __restrict__ buf,
               int2* __restrict__ nodeOff2, int n){
  __shared__ int cnts[BNODES], offs[BNODES], cursor[BNODES];
  int b = blockIdx.x, t = threadIdx.x;
  int cnt = min(gcur[b], CAP);
  int base = b*CAP;
  if (t < BNODES) cnts[t] = 0;
  __syncthreads();
  unsigned pk[6];
  #pragma unroll
  for (int k=0;k<6;k++){
    int i = t + k*256;
    if (i < cnt){
      pk[k] = buf[base + i];
      atomicAdd(&cnts[(pk[k]>>17)&63], 1);
    }
  }
  __syncthreads();
  if (t < BNODES){       // wave 0: shfl prefix over 64 nodes
    int v = cnts[t], sft = v;
    #pragma unroll
    for (int off=1; off<64; off<<=1){
      int u = __shfl_up(sft, off, 64);
      if (t >= off) sft += u;
    }
    offs[t] = sft - v; cursor[t] = sft - v;
    int node = b*BNODES + t;
    if (node < n) nodeOff2[node] = make_int2(base + sft - v, base + sft);
  }
  __syncthreads();
  #pragma unroll
  for (int k=0;k<6;k++){
    int i = t + k*256;
    if (i < cnt){
      int nd = (pk[k]>>17)&63;
      int r = atomicAdd(&cursor[nd], 1);
      buf[base + r] = pk[k] & 0x1FFFFu;
    }
  }
}

// ---------------- mean aggregation (node-sorted CSR, 16-lane groups — r0 best) ----------------
// 16 lanes per node; lane l holds cols [8l,8l+8) as one 16B chunk.
__global__ __launch_bounds__(256)
void aggregate_csr(const unsigned short* __restrict__ xb, const int2* __restrict__ nodeOff2,
                   const unsigned int* __restrict__ csr_src, unsigned short* __restrict__ aggb, int n){
  int g = (blockIdx.x*256 + threadIdx.x) >> 4;
  int l = threadIdx.x & 15;
  if (g >= n) return;
  int2 be = nodeOff2[g];
  int beg = be.x, end = be.y;
  float acc[8] = {0,0,0,0,0,0,0,0};
  #define ACCUM(u) { unsigned int w;                                   \
      w=(u).x; acc[0]+=__uint_as_float(w<<16); acc[1]+=__uint_as_float(w&0xffff0000u); \
      w=(u).y; acc[2]+=__uint_as_float(w<<16); acc[3]+=__uint_as_float(w&0xffff0000u); \
      w=(u).z; acc[4]+=__uint_as_float(w<<16); acc[5]+=__uint_as_float(w&0xffff0000u); \
      w=(u).w; acc[6]+=__uint_as_float(w<<16); acc[7]+=__uint_as_float(w&0xffff0000u); }
  int p = beg;
  for (; p+4 <= end; p += 4){
    int s0 = csr_src[p], s1 = csr_src[p+1], s2 = csr_src[p+2], s3 = csr_src[p+3];
    uint4 u0 = ((const uint4*)(xb + (size_t)s0*DN))[l];
    uint4 u1 = ((const uint4*)(xb + (size_t)s1*DN))[l];
    uint4 u2 = ((const uint4*)(xb + (size_t)s2*DN))[l];
    uint4 u3 = ((const uint4*)(xb + (size_t)s3*DN))[l];
    ACCUM(u0) ACCUM(u1) ACCUM(u2) ACCUM(u3)
  }
  for (; p < end; ++p){
    int s0 = csr_src[p];
    uint4 u0 = ((const uint4*)(xb + (size_t)s0*DN))[l];
    ACCUM(u0)
  }
  #undef ACCUM
  float inv = 1.f / fmaxf((float)(end-beg), 1.f);
  uint4 o;
  o.x = pack2(f2bf(acc[0]*inv), f2bf(acc[1]*inv));
  o.y = pack2(f2bf(acc[2]*inv), f2bf(acc[3]*inv));
  o.z = pack2(f2bf(acc[4]*inv), f2bf(acc[5]*inv));
  o.w = pack2(f2bf(acc[6]*inv), f2bf(acc[7]*inv));
  ((uint4*)(aggb + (size_t)g*DN))[l] = o;
}

// ---------------- dual-GEMM via bf16 MFMA, LDS-coalesced epilogue ----------------
// Changes vs r4 (A/B-attributable): LDS-staged output tile -> contiguous dwordx4
// stores (was scattered 2B/4B); rt_per_block 5 -> 2 (grid 1250 -> 3125) for more
// resident blocks to hide the per-tile A-load latency chain.
template<bool RELU, bool OUT_BF16>
__global__ __launch_bounds__(256)
void gemm_mfma(const unsigned short* __restrict__ A1, const unsigned short* __restrict__ W1b,
               const unsigned short* __restrict__ A2, const unsigned short* __restrict__ W2b,
               const float* __restrict__ bias, void* __restrict__ out,
               int rt_total, int rt_per_block)
{
  __shared__ unsigned char obuf[8192];           // 16x128 tile: bf16=4KB, fp32=8KB
  int t = threadIdx.x;
  int wave = t >> 6;
  int lane = t & 63;
  int m = lane & 15, quad = lane >> 4;

  bf16x8 Bf[2][2][4];   // persistent B fragments: [ct2][mat][kc]
  {
    const unsigned short* Ws[2] = {W1b, W2b};
    #pragma unroll
    for (int c2=0;c2<2;c2++){
      int col = wave*32 + c2*16 + m;
      #pragma unroll
      for (int mat=0;mat<2;mat++){
        const unsigned short* wrow = Ws[mat] + (size_t)col*DN + quad*8;
        #pragma unroll
        for (int kc=0;kc<4;kc++)
          Bf[c2][mat][kc] = *(const bf16x8*)(wrow + kc*32);
      }
    }
  }
  float bv0 = bias[wave*32 + m];
  float bv1 = bias[wave*32 + 16 + m];

  int rt_begin = blockIdx.x * rt_per_block;
  int rt_end = rt_begin + rt_per_block; if (rt_end > rt_total) rt_end = rt_total;

  for (int rt = rt_begin; rt < rt_end; ++rt){
    const unsigned short* a1p = A1 + ((size_t)(rt*16 + m))*DN + quad*8;
    const unsigned short* a2p = A2 + ((size_t)(rt*16 + m))*DN + quad*8;
    bf16x8 Af[2][4];
    #pragma unroll
    for (int kc=0;kc<4;kc++){
      Af[0][kc] = *(const bf16x8*)(a1p + kc*32);
      Af[1][kc] = *(const bf16x8*)(a2p + kc*32);
    }
    floatx4 acc0 = {0.f,0.f,0.f,0.f}, acc1 = {0.f,0.f,0.f,0.f};
    #pragma unroll
    for (int mat=0; mat<2; mat++)
      #pragma unroll
      for (int kc=0; kc<4; kc++){
        acc0 = __builtin_amdgcn_mfma_f32_16x16x32_bf16(Af[mat][kc], Bf[0][mat][kc], acc0, 0,0,0);
        acc1 = __builtin_amdgcn_mfma_f32_16x16x32_bf16(Af[mat][kc], Bf[1][mat][kc], acc1, 0,0,0);
      }
    if (OUT_BF16){
      unsigned short (*ob)[128] = (unsigned short (*)[128])obuf;
      #pragma unroll
      for (int r=0;r<4;r++){
        float v0 = acc0[r] + bv0;
        float v1 = acc1[r] + bv1;
        if (RELU){ v0 = fmaxf(v0, 0.f); v1 = fmaxf(v1, 0.f); }
        ob[quad*4+r][wave*32 + m]      = f2bf(v0);
        ob[quad*4+r][wave*32 + 16 + m] = f2bf(v1);
      }
      __syncthreads();
      // 16 rows x 128 cols bf16 = 4KB contiguous at row rt*16
      ((uint4*)((unsigned short*)out + (size_t)rt*16*DN))[t] = ((const uint4*)obuf)[t];
      __syncthreads();   // WAR: obuf reused next tile
    } else {
      float (*of)[128] = (float (*)[128])obuf;
      #pragma unroll
      for (int r=0;r<4;r++){
        float v0 = acc0[r] + bv0;
        float v1 = acc1[r] + bv1;
        if (RELU){ v0 = fmaxf(v0, 0.f); v1 = fmaxf(v1, 0.f); }
        of[quad*4+r][wave*32 + m]      = v0;
        of[quad*4+r][wave*32 + 16 + m] = v1;
      }
      __syncthreads();
      uint4* og = (uint4*)((float*)out + (size_t)rt*16*DN);   // 8KB contiguous
      og[t]       = ((const uint4*)obuf)[t];
      og[t + 256] = ((const uint4*)obuf)[t + 256];
      __syncthreads();
    }
  }
}

// ---------------- launch ----------------

extern "C" void kernel_launch(void* const* d_in, const int* in_sizes, int n_in,
                              void* d_out, int out_size, void* d_ws, size_t ws_size,
                              hipStream_t stream) {
  const float* x   = (const float*)d_in[0];
  const int*   ei  = (const int*)d_in[1];
  const float* Wl1 = (const float*)d_in[2];
  const float* bl1 = (const float*)d_in[3];
  const float* Wr1 = (const float*)d_in[4];
  const float* Wl2 = (const float*)d_in[5];
  const float* bl2 = (const float*)d_in[6];
  const float* Wr2 = (const float*)d_in[7];

  const int n = in_sizes[0] / DN;     // 100000
  const int E = in_sizes[1] / 2;      // 1600000
  const int* src = ei;
  const int* dst = ei + E;
  const int nbuck = divup(n, BNODES); // 1563 (<= HBMAX)

  // workspace: gcur | packed(padded, reused in-place as csr) | nodeOff2 | Wb | xb | aggb [| hb]
  char* ws = (char*)d_ws;
  char* ws_end = ws + ws_size;
  int* gcur = (int*)ws;  ws += (size_t)HBMAX*4;
  ws = (char*)(((uintptr_t)ws + 255) & ~(uintptr_t)255);
  unsigned int* packed = (unsigned int*)ws; ws += (size_t)nbuck*CAP*4;  // ~9.6 MB
  ws = (char*)(((uintptr_t)ws + 255) & ~(uintptr_t)255);
  int2* nodeOff2   = (int2*)ws; ws += (size_t)n*8;                      // 0.8 MB
  ws = (char*)(((uintptr_t)ws + 255) & ~(uintptr_t)255);
  unsigned short* Wb   = (unsigned short*)ws; ws += 4*16384*2;
  unsigned short* xb   = (unsigned short*)ws; ws += (size_t)n*DN*2;
  unsigned short* aggb = (unsigned short*)ws; ws += (size_t)n*DN*2;
  unsigned short* hb = xb;   // in-place fallback (never taken at current ws_size)
  if (ws + (size_t)n*DN*2 <= ws_end) { hb = (unsigned short*)ws; ws += (size_t)n*DN*2; }

  unsigned short* Wl1b = Wb;
  unsigned short* Wr1b = Wb + 16384;
  unsigned short* Wl2b = Wb + 2*16384;
  unsigned short* Wr2b = Wb + 3*16384;

  const int count8 = n*DN/8;
  convert_all<<<divup(count8 + 8192, 256),256,0,stream>>>(x, Wl1, Wr1, Wl2, Wr2, xb, Wb, gcur, nbuck, count8);
  scatter_atomic<<<NSL,  256,0,stream>>>(src, dst, gcur, packed, E, nbuck);
  node_sort     <<<nbuck,256,0,stream>>>(gcur, packed, nodeOff2, n);

  const int rt_total = n / 16;                  // 6250
  const int rt_per_block = 2;                   // grid 3125: more latency-hiding blocks
  const int gblocks = divup(rt_total, rt_per_block);
  const int agrid = divup(n*16, 256);           // 6250

  // layer 1: h = relu(agg@Wl1^T + x@Wr1^T + b1), bf16 out
  aggregate_csr<<<agrid,256,0,stream>>>(xb, nodeOff2, packed, aggb, n);
  gemm_mfma<true, true ><<<gblocks,256,0,stream>>>(aggb, Wl1b, xb, Wr1b, bl1, hb, rt_total, rt_per_block);
  // layer 2: out = agg@Wl2^T + h@Wr2^T + b2, fp32 out
  aggregate_csr<<<agrid,256,0,stream>>>(hb, nodeOff2, packed, aggb, n);
  gemm_mfma<false,false><<<gblocks,256,0,stream>>>(aggb, Wl2b, hb, Wr2b, bl2, d_out, rt_total, rt_per_block);
}

// Round 7
// 328.627 us; speedup vs baseline: 1.3097x; 1.0949x over previous
//
#include <hip/hip_runtime.h>
#include <stdint.h>

#define DN 128
#define NBITS 6          // 64 nodes per bucket
#define BNODES 64
#define HBMAX 2048       // LDS array bound for bucket counters (nbuck <= 1563)
#define CAP 1536         // padded bucket capacity (bucket load ~Poisson(1024), max ~1150)
#define NSL 256          // edge slices for scatter

__host__ __device__ static inline int divup(int a, int b){ return (a+b-1)/b; }

typedef __attribute__((ext_vector_type(8))) short bf16x8;
typedef __attribute__((ext_vector_type(4))) float floatx4;

__device__ __forceinline__ unsigned short f2bf(float f){
  unsigned int x = __float_as_uint(f);
  unsigned int r = x + 0x7fffu + ((x >> 16) & 1u);   // RNE
  return (unsigned short)(r >> 16);
}
__device__ __forceinline__ unsigned int pack2(unsigned short a, unsigned short b){
  return (unsigned int)a | ((unsigned int)b << 16);
}

// ---------------- fused convert + bucket-scatter (independent work, one dispatch) -----------
// Blocks [0,NSL): scatter body — two-pass padded-bucket scatter with atomic range
// reservation (r4-proven). Blocks [NSL,...): fp32->bf16 convert of x + 4 weight mats.
// The 256 latency-bound scatter blocks are dispatched first (critical path); the
// BW-bound convert blocks fill the remaining CUs -> overlap instead of 2 serial launches.
// gcur is zeroed by hipMemsetAsync before this kernel.
__global__ __launch_bounds__(256)
void convert_scatter(const float* __restrict__ x,
                     const float* __restrict__ w0, const float* __restrict__ w1,
                     const float* __restrict__ w2, const float* __restrict__ w3,
                     unsigned short* __restrict__ xb, unsigned short* __restrict__ Wb,
                     const int* __restrict__ src, const int* __restrict__ dst,
                     int* __restrict__ gcur, unsigned int* __restrict__ packed,
                     int E, int nbuck, int count8){
  __shared__ int h[HBMAX];
  __shared__ int cur[HBMAX];
  int t = threadIdx.x;

  if (blockIdx.x < NSL){
    // -------- scatter body --------
    int s = blockIdx.x;
    for (int i=t; i<nbuck; i+=256) h[i] = 0;
    __syncthreads();
    int n4 = E >> 2, per4 = divup(n4, NSL);
    int lo = s*per4, hi = min(lo+per4, n4);
    const int4* dst4 = (const int4*)dst;
    for (int i = lo + t; i < hi; i += 256){
      int4 d4 = dst4[i];
      atomicAdd(&h[d4.x >> NBITS], 1);
      atomicAdd(&h[d4.y >> NBITS], 1);
      atomicAdd(&h[d4.z >> NBITS], 1);
      atomicAdd(&h[d4.w >> NBITS], 1);
    }
    if (s == NSL-1){  // global tail E%4
      for (int e = (n4<<2) + t; e < E; e += 256)
        atomicAdd(&h[dst[e] >> NBITS], 1);
    }
    __syncthreads();
    for (int i=t; i<nbuck; i+=256){
      int c = h[i];
      int base = c ? atomicAdd(&gcur[i], c) : 0;
      cur[i] = i*CAP + base;
    }
    __syncthreads();
    const int4* src4 = (const int4*)src;
    for (int i = lo + t; i < hi; i += 256){
      int4 d4 = dst4[i];
      int4 s4 = src4[i];
      int dd[4] = {d4.x, d4.y, d4.z, d4.w};
      int ss[4] = {s4.x, s4.y, s4.z, s4.w};
      #pragma unroll
      for (int j=0;j<4;j++){
        int d = dd[j], b = d >> NBITS;
        int pos = atomicAdd(&cur[b], 1);
        if (pos < (b+1)*CAP)   // overflow guard (cannot trigger at 8-sigma margin)
          packed[pos] = (unsigned)ss[j] | ((unsigned)(d & (BNODES-1)) << 17);
      }
    }
    if (s == NSL-1){
      for (int e = (n4<<2) + t; e < E; e += 256){
        int d = dst[e], b = d >> NBITS;
        int pos = atomicAdd(&cur[b], 1);
        if (pos < (b+1)*CAP)
          packed[pos] = (unsigned)src[e] | ((unsigned)(d & (BNODES-1)) << 17);
      }
    }
  } else {
    // -------- convert body --------
    int i = (blockIdx.x - NSL)*256 + t;
    const float* sp; unsigned short* dp; int off;
    if (i < count8){ sp = x; dp = xb; off = i; }
    else {
      int tid = i - count8;                     // 0..8191 -> weight mats
      if (tid >= 8192) return;
      int mat = tid >> 11; off = tid & 2047;
      sp = (mat==0)?w0:(mat==1)?w1:(mat==2)?w2:w3;
      dp = Wb + (size_t)mat*16384;
    }
    const float4* sv = (const float4*)sp + (size_t)off*2;
    float4 a = sv[0], b = sv[1];
    uint4 o;
    o.x = pack2(f2bf(a.x), f2bf(a.y));
    o.y = pack2(f2bf(a.z), f2bf(a.w));
    o.z = pack2(f2bf(b.x), f2bf(b.y));
    o.w = pack2(f2bf(b.z), f2bf(b.w));
    ((uint4*)dp)[off] = o;
  }
}

// ---------------- per-bucket node sort, IN-PLACE -> csr (same buffer) + nodeOff2 ------------
// Block per bucket. Entries staged into <=6 regs/thread before any write (reads complete
// before first __syncthreads -> in-place rewrite is safe). Emits int2{beg,end} per node.
__global__ __launch_bounds__(256)
void node_sort(const int* __restrict__ gcur, unsigned int* __restrict__ buf,
               int2* __restrict__ nodeOff2, int n){
  __shared__ int cnts[BNODES], offs[BNODES], cursor[BNODES];
  int b = blockIdx.x, t = threadIdx.x;
  int cnt = min(gcur[b], CAP);
  int base = b*CAP;
  if (t < BNODES) cnts[t] = 0;
  __syncthreads();
  unsigned pk[6];
  #pragma unroll
  for (int k=0;k<6;k++){
    int i = t + k*256;
    if (i < cnt){
      pk[k] = buf[base + i];
      atomicAdd(&cnts[(pk[k]>>17)&63], 1);
    }
  }
  __syncthreads();
  if (t < BNODES){       // wave 0: shfl prefix over 64 nodes
    int v = cnts[t], sft = v;
    #pragma unroll
    for (int off=1; off<64; off<<=1){
      int u = __shfl_up(sft, off, 64);
      if (t >= off) sft += u;
    }
    offs[t] = sft - v; cursor[t] = sft - v;
    int node = b*BNODES + t;
    if (node < n) nodeOff2[node] = make_int2(base + sft - v, base + sft);
  }
  __syncthreads();
  #pragma unroll
  for (int k=0;k<6;k++){
    int i = t + k*256;
    if (i < cnt){
      int nd = (pk[k]>>17)&63;
      int r = atomicAdd(&cursor[nd], 1);
      buf[base + r] = pk[k] & 0x1FFFFu;
    }
  }
}

// ---------------- mean aggregation (node-sorted CSR, 16-lane groups — r0 best) ----------------
// 16 lanes per node; lane l holds cols [8l,8l+8) as one 16B chunk.
__global__ __launch_bounds__(256)
void aggregate_csr(const unsigned short* __restrict__ xb, const int2* __restrict__ nodeOff2,
                   const unsigned int* __restrict__ csr_src, unsigned short* __restrict__ aggb, int n){
  int g = (blockIdx.x*256 + threadIdx.x) >> 4;
  int l = threadIdx.x & 15;
  if (g >= n) return;
  int2 be = nodeOff2[g];
  int beg = be.x, end = be.y;
  float acc[8] = {0,0,0,0,0,0,0,0};
  #define ACCUM(u) { unsigned int w;                                   \
      w=(u).x; acc[0]+=__uint_as_float(w<<16); acc[1]+=__uint_as_float(w&0xffff0000u); \
      w=(u).y; acc[2]+=__uint_as_float(w<<16); acc[3]+=__uint_as_float(w&0xffff0000u); \
      w=(u).z; acc[4]+=__uint_as_float(w<<16); acc[5]+=__uint_as_float(w&0xffff0000u); \
      w=(u).w; acc[6]+=__uint_as_float(w<<16); acc[7]+=__uint_as_float(w&0xffff0000u); }
  int p = beg;
  for (; p+4 <= end; p += 4){
    int s0 = csr_src[p], s1 = csr_src[p+1], s2 = csr_src[p+2], s3 = csr_src[p+3];
    uint4 u0 = ((const uint4*)(xb + (size_t)s0*DN))[l];
    uint4 u1 = ((const uint4*)(xb + (size_t)s1*DN))[l];
    uint4 u2 = ((const uint4*)(xb + (size_t)s2*DN))[l];
    uint4 u3 = ((const uint4*)(xb + (size_t)s3*DN))[l];
    ACCUM(u0) ACCUM(u1) ACCUM(u2) ACCUM(u3)
  }
  for (; p < end; ++p){
    int s0 = csr_src[p];
    uint4 u0 = ((const uint4*)(xb + (size_t)s0*DN))[l];
    ACCUM(u0)
  }
  #undef ACCUM
  float inv = 1.f / fmaxf((float)(end-beg), 1.f);
  uint4 o;
  o.x = pack2(f2bf(acc[0]*inv), f2bf(acc[1]*inv));
  o.y = pack2(f2bf(acc[2]*inv), f2bf(acc[3]*inv));
  o.z = pack2(f2bf(acc[4]*inv), f2bf(acc[5]*inv));
  o.w = pack2(f2bf(acc[6]*inv), f2bf(acc[7]*inv));
  ((uint4*)(aggb + (size_t)g*DN))[l] = o;
}

// ---------------- dual-GEMM via bf16 MFMA, no LDS (r4-exact, proven 336us config) ------------
template<bool RELU, bool OUT_BF16>
__global__ __launch_bounds__(256)
void gemm_mfma(const unsigned short* __restrict__ A1, const unsigned short* __restrict__ W1b,
               const unsigned short* __restrict__ A2, const unsigned short* __restrict__ W2b,
               const float* __restrict__ bias, void* __restrict__ out,
               int rt_total, int rt_per_block)
{
  int wave = threadIdx.x >> 6;
  int lane = threadIdx.x & 63;
  int m = lane & 15, quad = lane >> 4;

  bf16x8 Bf[2][2][4];   // persistent B fragments: [ct2][mat][kc]
  {
    const unsigned short* Ws[2] = {W1b, W2b};
    #pragma unroll
    for (int c2=0;c2<2;c2++){
      int col = wave*32 + c2*16 + m;
      #pragma unroll
      for (int mat=0;mat<2;mat++){
        const unsigned short* wrow = Ws[mat] + (size_t)col*DN + quad*8;
        #pragma unroll
        for (int kc=0;kc<4;kc++)
          Bf[c2][mat][kc] = *(const bf16x8*)(wrow + kc*32);
      }
    }
  }
  float bv0 = bias[wave*32 + m];
  float bv1 = bias[wave*32 + 16 + m];

  int rt_begin = blockIdx.x * rt_per_block;
  int rt_end = rt_begin + rt_per_block; if (rt_end > rt_total) rt_end = rt_total;

  for (int rt = rt_begin; rt < rt_end; ++rt){
    const unsigned short* a1p = A1 + ((size_t)(rt*16 + m))*DN + quad*8;
    const unsigned short* a2p = A2 + ((size_t)(rt*16 + m))*DN + quad*8;
    bf16x8 Af[2][4];
    #pragma unroll
    for (int kc=0;kc<4;kc++){
      Af[0][kc] = *(const bf16x8*)(a1p + kc*32);
      Af[1][kc] = *(const bf16x8*)(a2p + kc*32);
    }
    __syncthreads();   // drains loads; all waves past load phase before stores
    floatx4 acc0 = {0.f,0.f,0.f,0.f}, acc1 = {0.f,0.f,0.f,0.f};
    #pragma unroll
    for (int mat=0; mat<2; mat++)
      #pragma unroll
      for (int kc=0; kc<4; kc++){
        acc0 = __builtin_amdgcn_mfma_f32_16x16x32_bf16(Af[mat][kc], Bf[0][mat][kc], acc0, 0,0,0);
        acc1 = __builtin_amdgcn_mfma_f32_16x16x32_bf16(Af[mat][kc], Bf[1][mat][kc], acc1, 0,0,0);
      }
    #pragma unroll
    for (int r=0;r<4;r++){
      int row = rt*16 + quad*4 + r;
      float v0 = acc0[r] + bv0;
      float v1 = acc1[r] + bv1;
      if (RELU){ v0 = fmaxf(v0, 0.f); v1 = fmaxf(v1, 0.f); }
      if (OUT_BF16){
        unsigned short* o = (unsigned short*)out + (size_t)row*DN + wave*32 + m;
        o[0]  = f2bf(v0);
        o[16] = f2bf(v1);
      } else {
        float* o = (float*)out + (size_t)row*DN + wave*32 + m;
        o[0]  = v0;
        o[16] = v1;
      }
    }
  }
}

// ---------------- launch ----------------

extern "C" void kernel_launch(void* const* d_in, const int* in_sizes, int n_in,
                              void* d_out, int out_size, void* d_ws, size_t ws_size,
                              hipStream_t stream) {
  const float* x   = (const float*)d_in[0];
  const int*   ei  = (const int*)d_in[1];
  const float* Wl1 = (const float*)d_in[2];
  const float* bl1 = (const float*)d_in[3];
  const float* Wr1 = (const float*)d_in[4];
  const float* Wl2 = (const float*)d_in[5];
  const float* bl2 = (const float*)d_in[6];
  const float* Wr2 = (const float*)d_in[7];

  const int n = in_sizes[0] / DN;     // 100000
  const int E = in_sizes[1] / 2;      // 1600000
  const int* src = ei;
  const int* dst = ei + E;
  const int nbuck = divup(n, BNODES); // 1563 (<= HBMAX)

  // workspace: gcur | packed(padded, reused in-place as csr) | nodeOff2 | Wb | xb | aggb [| hb]
  char* ws = (char*)d_ws;
  char* ws_end = ws + ws_size;
  int* gcur = (int*)ws;  ws += (size_t)HBMAX*4;
  ws = (char*)(((uintptr_t)ws + 255) & ~(uintptr_t)255);
  unsigned int* packed = (unsigned int*)ws; ws += (size_t)nbuck*CAP*4;  // ~9.6 MB
  ws = (char*)(((uintptr_t)ws + 255) & ~(uintptr_t)255);
  int2* nodeOff2   = (int2*)ws; ws += (size_t)n*8;                      // 0.8 MB
  ws = (char*)(((uintptr_t)ws + 255) & ~(uintptr_t)255);
  unsigned short* Wb   = (unsigned short*)ws; ws += 4*16384*2;
  unsigned short* xb   = (unsigned short*)ws; ws += (size_t)n*DN*2;
  unsigned short* aggb = (unsigned short*)ws; ws += (size_t)n*DN*2;
  unsigned short* hb = xb;   // in-place fallback (never taken at current ws_size)
  if (ws + (size_t)n*DN*2 <= ws_end) { hb = (unsigned short*)ws; ws += (size_t)n*DN*2; }

  unsigned short* Wl1b = Wb;
  unsigned short* Wr1b = Wb + 16384;
  unsigned short* Wl2b = Wb + 2*16384;
  unsigned short* Wr2b = Wb + 3*16384;

  const int count8 = n*DN/8;
  hipMemsetAsync(gcur, 0, (size_t)HBMAX*4, stream);   // zero bucket cursors (graph-safe)
  const int cgrid = NSL + divup(count8 + 8192, 256);  // 256 scatter blocks + convert blocks
  convert_scatter<<<cgrid,256,0,stream>>>(x, Wl1, Wr1, Wl2, Wr2, xb, Wb,
                                          src, dst, gcur, packed, E, nbuck, count8);
  node_sort<<<nbuck,256,0,stream>>>(gcur, packed, nodeOff2, n);

  const int rt_total = n / 16;                  // 6250
  const int rt_per_block = 5;                   // r4-proven
  const int gblocks = divup(rt_total, rt_per_block);
  const int agrid = divup(n*16, 256);           // 6250

  // layer 1: h = relu(agg@Wl1^T + x@Wr1^T + b1), bf16 out
  aggregate_csr<<<agrid,256,0,stream>>>(xb, nodeOff2, packed, aggb, n);
  gemm_mfma<true, true ><<<gblocks,256,0,stream>>>(aggb, Wl1b, xb, Wr1b, bl1, hb, rt_total, rt_per_block);
  // layer 2: out = agg@Wl2^T + h@Wr2^T + b2, fp32 out
  aggregate_csr<<<agrid,256,0,stream>>>(hb, nodeOff2, packed, aggb, n);
  gemm_mfma<false,false><<<gblocks,256,0,stream>>>(aggb, Wl2b, hb, Wr2b, bl2, d_out, rt_total, rt_per_block);
}

// Round 8
// 324.738 us; speedup vs baseline: 1.3254x; 1.0120x over previous
//
#include <hip/hip_runtime.h>
#include <stdint.h>

#define DN 128
#define NBITS 6          // 64 nodes per bucket
#define BNODES 64
#define HBMAX 2048       // LDS array bound for bucket counters (nbuck <= 1563)
#define CAP 1536         // padded bucket capacity (bucket load ~Poisson(1024), max ~1150)
#define NSL 256          // edge slices for scatter

__host__ __device__ static inline int divup(int a, int b){ return (a+b-1)/b; }

typedef __attribute__((ext_vector_type(8))) short bf16x8;
typedef __attribute__((ext_vector_type(4))) float floatx4;

__device__ __forceinline__ unsigned short f2bf(float f){
  unsigned int x = __float_as_uint(f);
  unsigned int r = x + 0x7fffu + ((x >> 16) & 1u);   // RNE
  return (unsigned short)(r >> 16);
}
__device__ __forceinline__ unsigned int pack2(unsigned short a, unsigned short b){
  return (unsigned int)a | ((unsigned int)b << 16);
}

// ---------------- fused convert + bucket-scatter (r7-proven, unchanged) ----------------
__global__ __launch_bounds__(256)
void convert_scatter(const float* __restrict__ x,
                     const float* __restrict__ w0, const float* __restrict__ w1,
                     const float* __restrict__ w2, const float* __restrict__ w3,
                     unsigned short* __restrict__ xb, unsigned short* __restrict__ Wb,
                     const int* __restrict__ src, const int* __restrict__ dst,
                     int* __restrict__ gcur, unsigned int* __restrict__ packed,
                     int E, int nbuck, int count8){
  __shared__ int h[HBMAX];
  __shared__ int cur[HBMAX];
  int t = threadIdx.x;

  if (blockIdx.x < NSL){
    // -------- scatter body --------
    int s = blockIdx.x;
    for (int i=t; i<nbuck; i+=256) h[i] = 0;
    __syncthreads();
    int n4 = E >> 2, per4 = divup(n4, NSL);
    int lo = s*per4, hi = min(lo+per4, n4);
    const int4* dst4 = (const int4*)dst;
    for (int i = lo + t; i < hi; i += 256){
      int4 d4 = dst4[i];
      atomicAdd(&h[d4.x >> NBITS], 1);
      atomicAdd(&h[d4.y >> NBITS], 1);
      atomicAdd(&h[d4.z >> NBITS], 1);
      atomicAdd(&h[d4.w >> NBITS], 1);
    }
    if (s == NSL-1){  // global tail E%4
      for (int e = (n4<<2) + t; e < E; e += 256)
        atomicAdd(&h[dst[e] >> NBITS], 1);
    }
    __syncthreads();
    for (int i=t; i<nbuck; i+=256){
      int c = h[i];
      int base = c ? atomicAdd(&gcur[i], c) : 0;
      cur[i] = i*CAP + base;
    }
    __syncthreads();
    const int4* src4 = (const int4*)src;
    for (int i = lo + t; i < hi; i += 256){
      int4 d4 = dst4[i];
      int4 s4 = src4[i];
      int dd[4] = {d4.x, d4.y, d4.z, d4.w};
      int ss[4] = {s4.x, s4.y, s4.z, s4.w};
      #pragma unroll
      for (int j=0;j<4;j++){
        int d = dd[j], b = d >> NBITS;
        int pos = atomicAdd(&cur[b], 1);
        if (pos < (b+1)*CAP)   // overflow guard (cannot trigger at 8-sigma margin)
          packed[pos] = (unsigned)ss[j] | ((unsigned)(d & (BNODES-1)) << 17);
      }
    }
    if (s == NSL-1){
      for (int e = (n4<<2) + t; e < E; e += 256){
        int d = dst[e], b = d >> NBITS;
        int pos = atomicAdd(&cur[b], 1);
        if (pos < (b+1)*CAP)
          packed[pos] = (unsigned)src[e] | ((unsigned)(d & (BNODES-1)) << 17);
      }
    }
  } else {
    // -------- convert body --------
    int i = (blockIdx.x - NSL)*256 + t;
    const float* sp; unsigned short* dp; int off;
    if (i < count8){ sp = x; dp = xb; off = i; }
    else {
      int tid = i - count8;                     // 0..8191 -> weight mats
      if (tid >= 8192) return;
      int mat = tid >> 11; off = tid & 2047;
      sp = (mat==0)?w0:(mat==1)?w1:(mat==2)?w2:w3;
      dp = Wb + (size_t)mat*16384;
    }
    const float4* sv = (const float4*)sp + (size_t)off*2;
    float4 a = sv[0], b = sv[1];
    uint4 o;
    o.x = pack2(f2bf(a.x), f2bf(a.y));
    o.y = pack2(f2bf(a.z), f2bf(a.w));
    o.z = pack2(f2bf(b.x), f2bf(b.y));
    o.w = pack2(f2bf(b.z), f2bf(b.w));
    ((uint4*)dp)[off] = o;
  }
}

// ---------------- bodies for the fused sort||gemm dispatch ----------------

// per-bucket node sort, IN-PLACE (r7-proven body)
__device__ __forceinline__
void node_sort_body(const int* __restrict__ gcur, unsigned int* __restrict__ buf,
                    int2* __restrict__ nodeOff2, int n){
  __shared__ int cnts[BNODES], cursor[BNODES];
  int b = blockIdx.x, t = threadIdx.x;
  int cnt = min(gcur[b], CAP);
  int base = b*CAP;
  if (t < BNODES) cnts[t] = 0;
  __syncthreads();
  unsigned pk[6];
  #pragma unroll
  for (int k=0;k<6;k++){
    int i = t + k*256;
    if (i < cnt){
      pk[k] = buf[base + i];
      atomicAdd(&cnts[(pk[k]>>17)&63], 1);
    }
  }
  __syncthreads();
  if (t < BNODES){       // wave 0: shfl prefix over 64 nodes
    int v = cnts[t], sft = v;
    #pragma unroll
    for (int off=1; off<64; off<<=1){
      int u = __shfl_up(sft, off, 64);
      if (t >= off) sft += u;
    }
    cursor[t] = sft - v;
    int node = b*BNODES + t;
    if (node < n) nodeOff2[node] = make_int2(base + sft - v, base + sft);
  }
  __syncthreads();
  #pragma unroll
  for (int k=0;k<6;k++){
    int i = t + k*256;
    if (i < cnt){
      int nd = (pk[k]>>17)&63;
      int r = atomicAdd(&cursor[nd], 1);
      buf[base + r] = pk[k] & 0x1FFFFu;
    }
  }
}

// pre-GEMM: y = A@Wl^T (bf16), z = A@Wr^T + bias (bf16). ONE A-read, two outputs.
// z may alias A (in-place): __syncthreads drains all waves' A-loads before stores,
// and each row is read/written only by its owner block -> safe (r4 gemm pattern).
__device__ __forceinline__
void gemm_pre_body(int blk, const unsigned short* __restrict__ A,
                   const unsigned short* __restrict__ Wlb, const unsigned short* __restrict__ Wrb,
                   const float* __restrict__ bias,
                   unsigned short* __restrict__ y, unsigned short* __restrict__ z,
                   int rt_total, int rt_per_block)
{
  int t = threadIdx.x;
  int wave = t >> 6, lane = t & 63;
  int m = lane & 15, quad = lane >> 4;

  bf16x8 Bf[2][2][4];   // [col-half][mat][kc]; mat0=Wl (y), mat1=Wr (z)
  {
    const unsigned short* Ws[2] = {Wlb, Wrb};
    #pragma unroll
    for (int c2=0;c2<2;c2++){
      int col = wave*32 + c2*16 + m;
      #pragma unroll
      for (int mat=0;mat<2;mat++){
        const unsigned short* wrow = Ws[mat] + (size_t)col*DN + quad*8;
        #pragma unroll
        for (int kc=0;kc<4;kc++)
          Bf[c2][mat][kc] = *(const bf16x8*)(wrow + kc*32);
      }
    }
  }
  float bv0 = bias[wave*32 + m];
  float bv1 = bias[wave*32 + 16 + m];

  int rt_begin = blk * rt_per_block;
  int rt_end = rt_begin + rt_per_block; if (rt_end > rt_total) rt_end = rt_total;

  for (int rt = rt_begin; rt < rt_end; ++rt){
    const unsigned short* ap = A + ((size_t)(rt*16 + m))*DN + quad*8;
    bf16x8 Af[4];
    #pragma unroll
    for (int kc=0;kc<4;kc++) Af[kc] = *(const bf16x8*)(ap + kc*32);
    __syncthreads();   // drains loads; all waves past load phase before in-place z stores
    floatx4 aY0 = {0.f,0.f,0.f,0.f}, aY1 = {0.f,0.f,0.f,0.f};
    floatx4 aZ0 = {0.f,0.f,0.f,0.f}, aZ1 = {0.f,0.f,0.f,0.f};
    #pragma unroll
    for (int kc=0; kc<4; kc++){
      aY0 = __builtin_amdgcn_mfma_f32_16x16x32_bf16(Af[kc], Bf[0][0][kc], aY0, 0,0,0);
      aY1 = __builtin_amdgcn_mfma_f32_16x16x32_bf16(Af[kc], Bf[1][0][kc], aY1, 0,0,0);
      aZ0 = __builtin_amdgcn_mfma_f32_16x16x32_bf16(Af[kc], Bf[0][1][kc], aZ0, 0,0,0);
      aZ1 = __builtin_amdgcn_mfma_f32_16x16x32_bf16(Af[kc], Bf[1][1][kc], aZ1, 0,0,0);
    }
    #pragma unroll
    for (int r=0;r<4;r++){
      int row = rt*16 + quad*4 + r;
      unsigned short* yo = y + (size_t)row*DN + wave*32 + m;
      yo[0]  = f2bf(aY0[r]);
      yo[16] = f2bf(aY1[r]);
      unsigned short* zo = z + (size_t)row*DN + wave*32 + m;
      zo[0]  = f2bf(aZ0[r] + bv0);
      zo[16] = f2bf(aZ1[r] + bv1);
    }
  }
}

// fused dispatch: blocks [0,nbuck) sort buckets; blocks [nbuck,..) run layer-1 pre-GEMM.
// Both depend only on convert_scatter; bodies touch disjoint buffers.
__global__ __launch_bounds__(256)
void sort_gemm1(const int* __restrict__ gcur, unsigned int* __restrict__ buf,
                int2* __restrict__ nodeOff2, int n, int nbuck,
                const unsigned short* __restrict__ A,
                const unsigned short* __restrict__ Wlb, const unsigned short* __restrict__ Wrb,
                const float* __restrict__ bias,
                unsigned short* __restrict__ y, unsigned short* __restrict__ z,
                int rt_total, int rt_per_block)
{
  if ((int)blockIdx.x < nbuck)
    node_sort_body(gcur, buf, nodeOff2, n);
  else
    gemm_pre_body(blockIdx.x - nbuck, A, Wlb, Wrb, bias, y, z, rt_total, rt_per_block);
}

// standalone pre-GEMM for layer 2
__global__ __launch_bounds__(256)
void gemm_pre(const unsigned short* __restrict__ A,
              const unsigned short* __restrict__ Wlb, const unsigned short* __restrict__ Wrb,
              const float* __restrict__ bias,
              unsigned short* __restrict__ y, unsigned short* __restrict__ z,
              int rt_total, int rt_per_block)
{
  gemm_pre_body(blockIdx.x, A, Wlb, Wrb, bias, y, z, rt_total, rt_per_block);
}

// ---------------- mean aggregation + epilogue (gather loop FROZEN from r0) ----------------
// out[g] = (RELU?)( mean_j y[j] + z[g] ); OUT_BF16 ? bf16 : fp32.
// mean(x)@Wl^T == mean(x@Wl^T) (linearity) -> GEMM hoisted before the gather,
// aggregate writes the final layer output directly (aggb round trip eliminated).
template<bool RELU, bool OUT_BF16>
__global__ __launch_bounds__(256)
void aggregate_pre(const unsigned short* __restrict__ yb, const unsigned short* __restrict__ zb,
                   const int2* __restrict__ nodeOff2, const unsigned int* __restrict__ csr_src,
                   void* __restrict__ out, int n){
  int g = (blockIdx.x*256 + threadIdx.x) >> 4;
  int l = threadIdx.x & 15;
  if (g >= n) return;
  int2 be = nodeOff2[g];
  int beg = be.x, end = be.y;
  float acc[8] = {0,0,0,0,0,0,0,0};
  #define ACCUM(u) { unsigned int w;                                   \
      w=(u).x; acc[0]+=__uint_as_float(w<<16); acc[1]+=__uint_as_float(w&0xffff0000u); \
      w=(u).y; acc[2]+=__uint_as_float(w<<16); acc[3]+=__uint_as_float(w&0xffff0000u); \
      w=(u).z; acc[4]+=__uint_as_float(w<<16); acc[5]+=__uint_as_float(w&0xffff0000u); \
      w=(u).w; acc[6]+=__uint_as_float(w<<16); acc[7]+=__uint_as_float(w&0xffff0000u); }
  int p = beg;
  for (; p+4 <= end; p += 4){
    int s0 = csr_src[p], s1 = csr_src[p+1], s2 = csr_src[p+2], s3 = csr_src[p+3];
    uint4 u0 = ((const uint4*)(yb + (size_t)s0*DN))[l];
    uint4 u1 = ((const uint4*)(yb + (size_t)s1*DN))[l];
    uint4 u2 = ((const uint4*)(yb + (size_t)s2*DN))[l];
    uint4 u3 = ((const uint4*)(yb + (size_t)s3*DN))[l];
    ACCUM(u0) ACCUM(u1) ACCUM(u2) ACCUM(u3)
  }
  for (; p < end; ++p){
    int s0 = csr_src[p];
    uint4 u0 = ((const uint4*)(yb + (size_t)s0*DN))[l];
    ACCUM(u0)
  }
  #undef ACCUM
  float inv = 1.f / fmaxf((float)(end-beg), 1.f);
  // read root+bias term z[g] (8 bf16 in one uint4)
  uint4 zc = ((const uint4*)(zb + (size_t)g*DN))[l];
  float v[8];
  { unsigned int w;
    w=zc.x; v[0]=__uint_as_float(w<<16); v[1]=__uint_as_float(w&0xffff0000u);
    w=zc.y; v[2]=__uint_as_float(w<<16); v[3]=__uint_as_float(w&0xffff0000u);
    w=zc.z; v[4]=__uint_as_float(w<<16); v[5]=__uint_as_float(w&0xffff0000u);
    w=zc.w; v[6]=__uint_as_float(w<<16); v[7]=__uint_as_float(w&0xffff0000u); }
  #pragma unroll
  for (int k=0;k<8;k++){
    v[k] += acc[k]*inv;
    if (RELU) v[k] = fmaxf(v[k], 0.f);
  }
  if (OUT_BF16){
    uint4 o;
    o.x = pack2(f2bf(v[0]), f2bf(v[1]));
    o.y = pack2(f2bf(v[2]), f2bf(v[3]));
    o.z = pack2(f2bf(v[4]), f2bf(v[5]));
    o.w = pack2(f2bf(v[6]), f2bf(v[7]));
    ((uint4*)((unsigned short*)out + (size_t)g*DN))[l] = o;
  } else {
    float* orow = (float*)out + (size_t)g*DN + l*8;
    float4 s0 = {v[0], v[1], v[2], v[3]};
    float4 s1 = {v[4], v[5], v[6], v[7]};
    ((float4*)orow)[0] = s0;
    ((float4*)orow)[1] = s1;
  }
}

// ---------------- launch ----------------

extern "C" void kernel_launch(void* const* d_in, const int* in_sizes, int n_in,
                              void* d_out, int out_size, void* d_ws, size_t ws_size,
                              hipStream_t stream) {
  const float* x   = (const float*)d_in[0];
  const int*   ei  = (const int*)d_in[1];
  const float* Wl1 = (const float*)d_in[2];
  const float* bl1 = (const float*)d_in[3];
  const float* Wr1 = (const float*)d_in[4];
  const float* Wl2 = (const float*)d_in[5];
  const float* bl2 = (const float*)d_in[6];
  const float* Wr2 = (const float*)d_in[7];

  const int n = in_sizes[0] / DN;     // 100000
  const int E = in_sizes[1] / 2;      // 1600000
  const int* src = ei;
  const int* dst = ei + E;
  const int nbuck = divup(n, BNODES); // 1563 (<= HBMAX)

  // workspace: gcur | packed | nodeOff2 | Wb | xb (later z) | yb | hb
  char* ws = (char*)d_ws;
  int* gcur = (int*)ws;  ws += (size_t)HBMAX*4;
  ws = (char*)(((uintptr_t)ws + 255) & ~(uintptr_t)255);
  unsigned int* packed = (unsigned int*)ws; ws += (size_t)nbuck*CAP*4;  // ~9.6 MB
  ws = (char*)(((uintptr_t)ws + 255) & ~(uintptr_t)255);
  int2* nodeOff2   = (int2*)ws; ws += (size_t)n*8;                      // 0.8 MB
  ws = (char*)(((uintptr_t)ws + 255) & ~(uintptr_t)255);
  unsigned short* Wb = (unsigned short*)ws; ws += 4*16384*2;
  unsigned short* xb = (unsigned short*)ws; ws += (size_t)n*DN*2;       // x, then z1/z2
  unsigned short* yb = (unsigned short*)ws; ws += (size_t)n*DN*2;       // y1, then y2
  unsigned short* hb = (unsigned short*)ws; ws += (size_t)n*DN*2;       // layer-1 output

  unsigned short* Wl1b = Wb;
  unsigned short* Wr1b = Wb + 16384;
  unsigned short* Wl2b = Wb + 2*16384;
  unsigned short* Wr2b = Wb + 3*16384;

  const int count8 = n*DN/8;
  const int rt_total = n / 16;                  // 6250
  const int rt_per_block = 5;                   // r4-proven
  const int gblocks = divup(rt_total, rt_per_block);
  const int agrid = divup(n*16, 256);           // 6250

  hipMemsetAsync(gcur, 0, (size_t)HBMAX*4, stream);   // zero bucket cursors (graph-safe)
  const int cgrid = NSL + divup(count8 + 8192, 256);
  convert_scatter<<<cgrid,256,0,stream>>>(x, Wl1, Wr1, Wl2, Wr2, xb, Wb,
                                          src, dst, gcur, packed, E, nbuck, count8);
  // node_sort || layer-1 pre-GEMM (independent): y1=xb@Wl1^T -> yb, z1=xb@Wr1^T+b1 -> xb (in-place)
  sort_gemm1<<<nbuck + gblocks,256,0,stream>>>(gcur, packed, nodeOff2, n, nbuck,
                                               xb, Wl1b, Wr1b, bl1, yb, xb,
                                               rt_total, rt_per_block);
  // layer 1: h = relu(mean(y1) + z1) -> hb (bf16)
  aggregate_pre<true, true ><<<agrid,256,0,stream>>>(yb, xb, nodeOff2, packed, hb, n);
  // layer-2 pre-GEMM: y2=hb@Wl2^T -> yb, z2=hb@Wr2^T+b2 -> xb
  gemm_pre<<<gblocks,256,0,stream>>>(hb, Wl2b, Wr2b, bl2, yb, xb, rt_total, rt_per_block);
  // layer 2: out = mean(y2) + z2 -> d_out (fp32)
  aggregate_pre<false,false><<<agrid,256,0,stream>>>(yb, xb, nodeOff2, packed, d_out, n);
}